// Round 1
// baseline (218.101 us; speedup 1.0000x reference)
//
#include <hip/hip_runtime.h>

// MessagePassing: B=262144 independent 5-node ring GNN evaluations.
// One thread per batch element; weights in LDS (broadcast reads);
// x staged via LDS for coalescing. Compute-bound on fp32 VALU (~24us floor).

#define NH 18

__device__ __forceinline__ float fast_tanh(float x) {
    // tanh(x) = 1 - 2/(exp(2x)+1); exp via v_exp_f32, rcp via v_rcp_f32.
    // Handles saturation: t->inf => 1, t->0 => -1. Error ~1e-6.
    float t = __builtin_amdgcn_exp2f(x * 2.8853900817779268f); // 2*log2(e)
    float r = __builtin_amdgcn_rcpf(t + 1.0f);
    return __builtin_fmaf(-2.0f, r, 1.0f);
}

__global__ __launch_bounds__(256) void mp_kernel(
    const float* __restrict__ x,
    const float* __restrict__ Wf, const float* __restrict__ bf,
    const float* __restrict__ Wm, const float* __restrict__ bm,
    const float* __restrict__ Wu, const float* __restrict__ bu,
    const float* __restrict__ Wr, const float* __restrict__ br,
    float* __restrict__ out, int B)
{
    __shared__ float sWf[6 * NH];    // [6][18]
    __shared__ float sbf[NH];
    __shared__ float sWm[36 * NH];   // [36][18]
    __shared__ float sbm[NH];
    __shared__ float sWuM[NH * NH];  // Wu rows 0..17  (multiply M_prev)
    __shared__ float sWuH[NH * NH];  // Wu rows 18..35 + rows 36..53 (both multiply h)
    __shared__ float sbu[NH];
    __shared__ float sWr[5 * NH];
    __shared__ float sx[256 * 30];   // per-block x stage, 30 KB

    const int tid = threadIdx.x;

    for (int i = tid; i < 6 * NH; i += 256) sWf[i] = Wf[i];
    for (int i = tid; i < 36 * NH; i += 256) sWm[i] = Wm[i];
    for (int i = tid; i < NH * NH; i += 256) {
        sWuM[i] = Wu[i];
        sWuH[i] = Wu[NH * NH + i] + Wu[2 * NH * NH + i]; // exact fold: U == h
    }
    for (int i = tid; i < 5 * NH; i += 256) sWr[i] = Wr[i];
    if (tid < NH) { sbf[tid] = bf[tid]; sbm[tid] = bm[tid]; sbu[tid] = bu[tid]; }

    const long long base = (long long)blockIdx.x * (256 * 30);
    const long long xtot = (long long)B * 30;
    for (int i = tid; i < 256 * 30; i += 256) {
        long long g = base + i;
        sx[i] = (g < xtot) ? x[g] : 0.0f;
    }
    __syncthreads();

    float xv[30];
    #pragma unroll
    for (int i = 0; i < 30; ++i) xv[i] = sx[tid * 30 + i];

    // ---- Stage 1: h[n][k] = tanh(x[n] @ Wf + bf) ----
    float h[5][NH];
    #pragma unroll
    for (int n = 0; n < 5; ++n) {
        float acc[NH];
        #pragma unroll
        for (int k = 0; k < NH; ++k) acc[k] = sbf[k];
        #pragma unroll
        for (int f = 0; f < 6; ++f) {
            float xf = xv[n * 6 + f];
            #pragma unroll
            for (int k = 0; k < NH; ++k)
                acc[k] = __builtin_fmaf(xf, sWf[f * NH + k], acc[k]);
        }
        #pragma unroll
        for (int k = 0; k < NH; ++k) h[n][k] = fast_tanh(acc[k]);
    }

    // ---- Stage 2/3 interleaved with ring buffer on M ----
    // M[n] = tanh([h[n], h[(n+1)%5]] @ Wm + bm)
    // U2[n] = tanh([M[n-1], h[n], h[n]] @ Wu + bu); out += U2[n] . Wr[n]
    float Mprev[NH];
    { // Mprev = M[4] from h[4], h[0]
        float acc[NH];
        #pragma unroll
        for (int k = 0; k < NH; ++k) acc[k] = sbm[k];
        #pragma unroll
        for (int j = 0; j < NH; ++j) {
            float a = h[4][j], b = h[0][j];
            #pragma unroll
            for (int k = 0; k < NH; ++k)
                acc[k] = __builtin_fmaf(b, sWm[(NH + j) * NH + k],
                          __builtin_fmaf(a, sWm[j * NH + k], acc[k]));
        }
        #pragma unroll
        for (int k = 0; k < NH; ++k) Mprev[k] = fast_tanh(acc[k]);
    }

    float racc = br[0];
    #pragma unroll
    for (int n = 0; n < 5; ++n) {
        { // U2[n] from Mprev (= M[n-1]) and h[n]
            float acc[NH];
            #pragma unroll
            for (int k = 0; k < NH; ++k) acc[k] = sbu[k];
            #pragma unroll
            for (int j = 0; j < NH; ++j) {
                float m = Mprev[j], hv = h[n][j];
                #pragma unroll
                for (int k = 0; k < NH; ++k)
                    acc[k] = __builtin_fmaf(hv, sWuH[j * NH + k],
                              __builtin_fmaf(m, sWuM[j * NH + k], acc[k]));
            }
            #pragma unroll
            for (int k = 0; k < NH; ++k)
                racc = __builtin_fmaf(fast_tanh(acc[k]), sWr[n * NH + k], racc);
        }
        if (n < 4) { // Mprev <- M[n] from h[n], h[n+1] (needed by U2[n+1])
            float acc[NH];
            #pragma unroll
            for (int k = 0; k < NH; ++k) acc[k] = sbm[k];
            #pragma unroll
            for (int j = 0; j < NH; ++j) {
                float a = h[n][j], b = h[n + 1][j];
                #pragma unroll
                for (int k = 0; k < NH; ++k)
                    acc[k] = __builtin_fmaf(b, sWm[(NH + j) * NH + k],
                              __builtin_fmaf(a, sWm[j * NH + k], acc[k]));
            }
            #pragma unroll
            for (int k = 0; k < NH; ++k) Mprev[k] = fast_tanh(acc[k]);
        }
    }

    long long b = (long long)blockIdx.x * 256 + tid;
    if (b < B) out[b] = racc;
}

extern "C" void kernel_launch(void* const* d_in, const int* in_sizes, int n_in,
                              void* d_out, int out_size, void* d_ws, size_t ws_size,
                              hipStream_t stream) {
    const float* x  = (const float*)d_in[0];
    const float* Wf = (const float*)d_in[1];
    const float* bf = (const float*)d_in[2];
    const float* Wm = (const float*)d_in[3];
    const float* bm = (const float*)d_in[4];
    const float* Wu = (const float*)d_in[5];
    const float* bu = (const float*)d_in[6];
    const float* Wr = (const float*)d_in[7];
    const float* br = (const float*)d_in[8];
    float* out = (float*)d_out;

    const int B = in_sizes[0] / 30;          // [B,5,6]
    const int grid = (B + 255) / 256;
    mp_kernel<<<grid, 256, 0, stream>>>(x, Wf, bf, Wm, bm, Wu, bu, Wr, br, out, B);
}